// Round 4
// baseline (280.506 us; speedup 1.0000x reference)
//
#include <hip/hip_runtime.h>
#include <hip/hip_fp16.h>

#define N_NODES 50000
#define N_EDGES 600000
#define N_GRAPHS 64
#define IN_D 5
#define HID 128
#define EMB 64

#define CHUNK 512
#define NCHUNK ((N_NODES + CHUNK - 1) / CHUNK)   // 98
#define NREP 16          // psum replication factor (contention spread)
#define NLOC 4           // per-block local graph slots (16 sorted nodes span <=2)
#define TB 16            // nodes per fused agg+gemm tile (50000 = 3125*16, no tail)

typedef _Float16 half8 __attribute__((ext_vector_type(8)));
typedef float float4v __attribute__((ext_vector_type(4)));

// ---------- 1. init: zero everything + fp16-transpose W2/W3 ----------

__global__ __launch_bounds__(256) void k_init(
        int* __restrict__ cnt, float* __restrict__ psum_rep,
        const float* __restrict__ W2, const float* __restrict__ W3,
        _Float16* __restrict__ Wt2, _Float16* __restrict__ Wt3,
        int2* __restrict__ e_pack) {
    int tid = blockIdx.x * blockDim.x + threadIdx.x;
    int nt = gridDim.x * blockDim.x;
    for (int i = tid; i < N_NODES; i += nt) cnt[i] = 0;
    for (int i = tid; i < NREP * N_GRAPHS * HID; i += nt) psum_rep[i] = 0.f;
    if (tid < 8) e_pack[N_EDGES + tid] = make_int2(0, 0);  // safe pad for slot-reads
    for (int i = tid; i < 2 * HID * HID; i += nt) {
        int rem = i & (HID * HID - 1);
        int k = rem & 127, f = rem >> 7;
        if (i < HID * HID) Wt2[rem] = (_Float16)W2[k * HID + f];
        else               Wt3[rem] = (_Float16)W3[k * HID + f];
    }
}

// ---------- 2. degree count ----------

__global__ __launch_bounds__(256) void k_count(
        const int* __restrict__ dst, int* __restrict__ cnt) {
    int e = blockIdx.x * blockDim.x + threadIdx.x;
    if (e < N_EDGES) atomicAdd(&cnt[dst[e]], 1);
}

// ---------- 3. per-chunk sums + dinv ----------

__global__ void k_chunksum(const int* __restrict__ cnt, int* __restrict__ csum,
                           float* __restrict__ dinv) {
    __shared__ int sh[256];
    int b = blockIdx.x, t = threadIdx.x;
    int i0 = b * CHUNK + t, i1 = i0 + 256;
    int v = 0;
    if (i0 < N_NODES) { int c = cnt[i0]; v += c; dinv[i0] = rsqrtf((float)c + 1.0f); }
    if (i1 < N_NODES) { int c = cnt[i1]; v += c; dinv[i1] = rsqrtf((float)c + 1.0f); }
    sh[t] = v; __syncthreads();
    for (int off = 128; off > 0; off >>= 1) {
        if (t < off) sh[t] += sh[t + off];
        __syncthreads();
    }
    if (t == 0) csum[b] = sh[0];
}

// ---------- 4. per-chunk exclusive scan -> row_start ----------

__global__ void k_scan(const int* __restrict__ cnt, const int* __restrict__ csum,
                       int* __restrict__ row_start) {
    __shared__ int ws[4];
    int b = blockIdx.x, t = threadIdx.x;
    int lane = t & 63, w = t >> 6;

    int pre = 0;
    for (int j = lane; j < b; j += 64) pre += csum[j];
    #pragma unroll
    for (int off = 32; off > 0; off >>= 1) pre += __shfl_down(pre, off);
    pre = __shfl(pre, 0);

    int base = b * CHUNK;
    int i0 = base + 2 * t, i1 = i0 + 1;
    int c0 = (i0 < N_NODES) ? cnt[i0] : 0;
    int c1 = (i1 < N_NODES) ? cnt[i1] : 0;
    int v = c0 + c1;
    int s = v;
    #pragma unroll
    for (int off = 1; off < 64; off <<= 1) {
        int u = __shfl_up(s, off);
        if (lane >= off) s += u;
    }
    if (lane == 63) ws[w] = s;
    __syncthreads();
    if (t == 0) {
        int r = 0;
        #pragma unroll
        for (int j = 0; j < 4; ++j) { int xx = ws[j]; ws[j] = r; r += xx; }
    }
    __syncthreads();
    int excl = s - v + ws[w] + pre;
    if (i0 < N_NODES) row_start[i0] = excl;
    if (i1 < N_NODES) row_start[i1] = excl + c0;
    if (b == 0 && t == 0) row_start[N_NODES] = N_EDGES;
}

// ---------- 5. scatter edges into CSR order (cnt reused as fill via atomicSub) ----------

__global__ __launch_bounds__(256) void k_scatter(
        const int* __restrict__ src, const int* __restrict__ dst,
        const float* __restrict__ dinv, const int* __restrict__ row_start,
        int* __restrict__ cnt, int2* __restrict__ e_pack) {
    int e = blockIdx.x * blockDim.x + threadIdx.x;
    if (e >= N_EDGES) return;
    int d = dst[e];
    int pos = row_start[d] + atomicSub(&cnt[d], 1) - 1;
    int s = src[e];
    e_pack[pos] = make_int2(s, __float_as_int(dinv[s]));
}

// ---------- 6. fused layer 1: agg(x) + gemm1 + bn + relu -> H16 ----------

__global__ __launch_bounds__(256) void k_agg5g1(
        const float* __restrict__ x, const float* __restrict__ dinv,
        const int* __restrict__ row_start, const int2* __restrict__ e_pack,
        const float* __restrict__ W1, const float* __restrict__ b1,
        const float* __restrict__ g1, const float* __restrict__ be1,
        __half2* __restrict__ H16) {
    int gid = blockIdx.x * blockDim.x + threadIdx.x;
    int i = gid >> 3, k = gid & 7;
    if (i >= N_NODES) return;
    float acc = 0.f;
    if (k < IN_D) {
        int beg = row_start[i], end = row_start[i + 1];
        int e = beg;
        for (; e + 3 < end; e += 4) {
            int2 p0 = e_pack[e];
            int2 p1 = e_pack[e + 1];
            int2 p2 = e_pack[e + 2];
            int2 p3 = e_pack[e + 3];
            float x0 = x[p0.x * IN_D + k];
            float x1 = x[p1.x * IN_D + k];
            float x2 = x[p2.x * IN_D + k];
            float x3 = x[p3.x * IN_D + k];
            acc = fmaf(__int_as_float(p0.y), x0, acc);
            acc = fmaf(__int_as_float(p1.y), x1, acc);
            acc = fmaf(__int_as_float(p2.y), x2, acc);
            acc = fmaf(__int_as_float(p3.y), x3, acc);
        }
        for (; e < end; ++e) {
            int2 p = e_pack[e];
            acc = fmaf(__int_as_float(p.y), x[p.x * IN_D + k], acc);
        }
        float di = dinv[i];
        acc = di * (acc + di * x[i * IN_D + k]);
    }
    int lane = threadIdx.x & 63;
    int base = lane & ~7;
    float a0 = __shfl(acc, base + 0);
    float a1 = __shfl(acc, base + 1);
    float a2 = __shfl(acc, base + 2);
    float a3 = __shfl(acc, base + 3);
    float a4 = __shfl(acc, base + 4);
    const float rs = rsqrtf(1.0f + 1e-5f);
    int f0 = k * 16;
    #pragma unroll
    for (int u = 0; u < 8; ++u) {
        int fa = f0 + u * 2, fb = fa + 1;
        float va = b1[fa], vb = b1[fb];
        va = fmaf(a0, W1[0 * HID + fa], va); vb = fmaf(a0, W1[0 * HID + fb], vb);
        va = fmaf(a1, W1[1 * HID + fa], va); vb = fmaf(a1, W1[1 * HID + fb], vb);
        va = fmaf(a2, W1[2 * HID + fa], va); vb = fmaf(a2, W1[2 * HID + fb], vb);
        va = fmaf(a3, W1[3 * HID + fa], va); vb = fmaf(a3, W1[3 * HID + fb], vb);
        va = fmaf(a4, W1[4 * HID + fa], va); vb = fmaf(a4, W1[4 * HID + fb], vb);
        va = fmaf(va, g1[fa] * rs, be1[fa]);
        vb = fmaf(vb, g1[fb] * rs, be1[fb]);
        va = va > 0.f ? va : 0.f;
        vb = vb > 0.f ? vb : 0.f;
        H16[(size_t)i * 64 + k * 8 + u] = __floats2half2_rn(va, vb);
    }
}

// ---------- multi-edge agg: one gather inst fetches 4 edge-rows (16B/lane) ----------
// lane = slot*16 + q16: slot in 0..3 picks an edge, q16 picks 8 features (16B).
// Per 8 edges: 2 e_pack insts + 2 gather insts (vs 16 insts for 1-edge/inst form).
// Cross-slot reduce = 16 shfl_xor per NODE. Masked slots read in-bounds pad
// entries (weight forced 0), so no per-edge branches in the hot loop.

__device__ __forceinline__ void agg_node_mf(
        const _Float16* __restrict__ Hin, const float* __restrict__ dinv,
        const int* __restrict__ row_start, const int2* __restrict__ e_pack,
        int n, int slot, int q16, _Float16* __restrict__ asrow) {
    float acc[8];
    #pragma unroll
    for (int j = 0; j < 8; ++j) acc[j] = 0.f;
    int beg = row_start[n], end = row_start[n + 1];
    for (int e = beg; e < end; e += 8) {
        int2 peA = e_pack[e + slot];
        float fwA = (e + slot < end) ? __int_as_float(peA.y) : 0.f;
        half8 gA = ((const half8*)(Hin + (size_t)peA.x * HID))[q16];
        #pragma unroll
        for (int j = 0; j < 8; ++j) acc[j] = fmaf(fwA, (float)gA[j], acc[j]);
        if (e + 4 < end) {
            int2 peB = e_pack[e + 4 + slot];
            float fwB = (e + 4 + slot < end) ? __int_as_float(peB.y) : 0.f;
            half8 gB = ((const half8*)(Hin + (size_t)peB.x * HID))[q16];
            #pragma unroll
            for (int j = 0; j < 8; ++j) acc[j] = fmaf(fwB, (float)gB[j], acc[j]);
        }
    }
    // reduce across the 4 edge-slots (lane bits 4 and 5)
    #pragma unroll
    for (int j = 0; j < 8; ++j) {
        acc[j] += __shfl_xor(acc[j], 16);
        acc[j] += __shfl_xor(acc[j], 32);
    }
    float di = dinv[n];
    half8 hs = ((const half8*)(Hin + (size_t)n * HID))[q16];
    half8 outv;
    #pragma unroll
    for (int j = 0; j < 8; ++j)
        outv[j] = (_Float16)(di * fmaf(di, (float)hs[j], acc[j]));
    if (slot == 0)
        *(half8*)(asrow + q16 * 8) = outv;
}

// ---------- 7. fused layer 2: agg(H16) -> LDS -> MFMA gemm + bn + relu -> outH ----------
// TB=16 nodes/block, 4 waves: each wave aggs 4 nodes (multi-edge gathers), then
// all waves share the LDS A-tile; each wave computes 2 of the 8 feature-tiles.

__global__ __launch_bounds__(256) void k_fuse2(
        const _Float16* __restrict__ Hin, const float* __restrict__ dinv,
        const int* __restrict__ row_start, const int2* __restrict__ e_pack,
        const _Float16* __restrict__ Wt,
        const float* __restrict__ bb, const float* __restrict__ gg,
        const float* __restrict__ bee, _Float16* __restrict__ outH) {
    __shared__ __align__(16) _Float16 As[TB][136];
    int t = threadIdx.x;
    int w = t >> 6, lane = t & 63;
    int slot = lane >> 4, q16 = lane & 15;
    int nb = blockIdx.x * TB;

    #pragma unroll 1
    for (int i = 0; i < 4; ++i)
        agg_node_mf(Hin, dinv, row_start, e_pack, nb + w * 4 + i,
                    slot, q16, &As[w * 4 + i][0]);
    __syncthreads();

    int quad = lane >> 4, r16 = lane & 15;
    half8 a[4];
    #pragma unroll
    for (int kb = 0; kb < 4; ++kb)
        a[kb] = *(const half8*)&As[r16][(kb * 4 + quad) * 8];
    const float rs = rsqrtf(1.0f + 1e-5f);
    #pragma unroll
    for (int fi = 0; fi < 2; ++fi) {
        int f = (w * 2 + fi) * 16 + r16;
        const half8* Brow = (const half8*)(Wt + (size_t)f * 128);
        float4v acc = {0.f, 0.f, 0.f, 0.f};
        #pragma unroll
        for (int kb = 0; kb < 4; ++kb)
            acc = __builtin_amdgcn_mfma_f32_16x16x32_f16(a[kb], Brow[kb * 4 + quad],
                                                         acc, 0, 0, 0);
        float b0 = bb[f], gf = gg[f] * rs, e0 = bee[f];
        #pragma unroll
        for (int rr = 0; rr < 4; ++rr) {
            float v = fmaf(acc[rr] + b0, gf, e0);
            v = v > 0.f ? v : 0.f;
            outH[(size_t)(nb + quad * 4 + rr) * 128 + f] = (_Float16)v;
        }
    }
}

// ---------- 8. fused layer 3: agg -> LDS -> MFMA gemm + bn + relu + mean-pool ----------

__global__ __launch_bounds__(256) void k_fuse3(
        const _Float16* __restrict__ Hin, const float* __restrict__ dinv,
        const int* __restrict__ row_start, const int2* __restrict__ e_pack,
        const _Float16* __restrict__ Wt,
        const float* __restrict__ bb, const float* __restrict__ gg,
        const float* __restrict__ bee, const int* __restrict__ batch,
        float* __restrict__ psum_rep) {
    __shared__ __align__(16) _Float16 As[TB][136];
    __shared__ float sh_pool[NLOC][HID];
    int t = threadIdx.x;
    int w = t >> 6, lane = t & 63;
    int slot = lane >> 4, q16 = lane & 15;
    int blk = (int)blockIdx.x;
    int nb = blk * TB;

    for (int i = t; i < NLOC * HID; i += 256) ((float*)sh_pool)[i] = 0.f;

    #pragma unroll 1
    for (int i = 0; i < 4; ++i)
        agg_node_mf(Hin, dinv, row_start, e_pack, nb + w * 4 + i,
                    slot, q16, &As[w * 4 + i][0]);

    int quad = lane >> 4, r16 = lane & 15;
    int g0 = batch[nb];
    int gi4[4];
    #pragma unroll
    for (int rr = 0; rr < 4; ++rr) gi4[rr] = batch[nb + quad * 4 + rr];
    __syncthreads();

    half8 a[4];
    #pragma unroll
    for (int kb = 0; kb < 4; ++kb)
        a[kb] = *(const half8*)&As[r16][(kb * 4 + quad) * 8];
    float* rep = psum_rep + (size_t)(blk & (NREP - 1)) * N_GRAPHS * HID;
    const float rs = rsqrtf(1.0f + 1e-5f);
    #pragma unroll
    for (int fi = 0; fi < 2; ++fi) {
        int f = (w * 2 + fi) * 16 + r16;
        const half8* Brow = (const half8*)(Wt + (size_t)f * 128);
        float4v acc = {0.f, 0.f, 0.f, 0.f};
        #pragma unroll
        for (int kb = 0; kb < 4; ++kb)
            acc = __builtin_amdgcn_mfma_f32_16x16x32_f16(a[kb], Brow[kb * 4 + quad],
                                                         acc, 0, 0, 0);
        float b0 = bb[f], gf = gg[f] * rs, e0 = bee[f];
        float partial = 0.f;
        int cur = -1;
        #pragma unroll
        for (int rr = 0; rr < 4; ++rr) {
            float v = fmaf(acc[rr] + b0, gf, e0);
            v = v > 0.f ? v : 0.f;
            int gi = gi4[rr];
            if (gi != cur) {
                if (cur >= 0) {
                    int idx = cur - g0;
                    if (idx < NLOC) atomicAdd(&sh_pool[idx][f], partial);
                    else            atomicAdd(&rep[cur * HID + f], partial);
                }
                partial = 0.f; cur = gi;
            }
            partial += v;
        }
        if (cur >= 0) {
            int idx = cur - g0;
            if (idx < NLOC) atomicAdd(&sh_pool[idx][f], partial);
            else            atomicAdd(&rep[cur * HID + f], partial);
        }
    }
    __syncthreads();
    // flush LDS partials: one replicated global atomic per (graph,f) present
    for (int i = t; i < NLOC * HID; i += 256) {
        int idx = i >> 7, ff = i & 127;
        float v = sh_pool[idx][ff];
        int g = g0 + idx;
        if (v != 0.f && g < N_GRAPHS) atomicAdd(&rep[g * HID + ff], v);
    }
}

// ---------- 9. projection (+ graph counts via binary search, no atomics) ----------

__device__ __forceinline__ int lower_bound_batch(const int* __restrict__ batch, int val) {
    int lo = 0, hi = N_NODES;
    while (lo < hi) {
        int mid = (lo + hi) >> 1;
        if (batch[mid] < val) lo = mid + 1;
        else hi = mid;
    }
    return lo;
}

__global__ void k_final(const float* __restrict__ psum_rep, const int* __restrict__ batch,
                        const float* __restrict__ Wp, const float* __restrict__ bp,
                        float* __restrict__ out) {
    __shared__ float s_p[HID];
    int gi = blockIdx.x, e = threadIdx.x;   // 64 threads
    for (int f = e; f < HID; f += EMB) {
        float v = 0.f;
        #pragma unroll
        for (int r = 0; r < NREP; ++r)
            v += psum_rep[(size_t)r * N_GRAPHS * HID + gi * HID + f];
        s_p[f] = v;
    }
    int lane = e & 63;
    int r = 0;
    if (lane < 2) r = lower_bound_batch(batch, gi + lane);
    int c0 = __shfl(r, 0), c1 = __shfl(r, 1);
    float inv = 1.0f / fmaxf((float)(c1 - c0), 1.0f);
    __syncthreads();
    float acc = bp[e];
    #pragma unroll 8
    for (int f = 0; f < HID; ++f)
        acc = fmaf(s_p[f] * inv, Wp[f * EMB + e], acc);
    out[gi * EMB + e] = acc;
}

// ---------- launcher ----------

extern "C" void kernel_launch(void* const* d_in, const int* in_sizes, int n_in,
                              void* d_out, int out_size, void* d_ws, size_t ws_size,
                              hipStream_t stream) {
    const float* x   = (const float*)d_in[0];
    const int*   src = (const int*)d_in[1];
    const int*   dst = (const int*)d_in[2];
    const int* batch = (const int*)d_in[3];
    const float* W1 = (const float*)d_in[4];
    const float* b1 = (const float*)d_in[5];
    const float* W2 = (const float*)d_in[6];
    const float* b2 = (const float*)d_in[7];
    const float* W3 = (const float*)d_in[8];
    const float* b3 = (const float*)d_in[9];
    const float* g1 = (const float*)d_in[10];
    const float* be1 = (const float*)d_in[11];
    const float* g2 = (const float*)d_in[12];
    const float* be2 = (const float*)d_in[13];
    const float* g3 = (const float*)d_in[14];
    const float* be3 = (const float*)d_in[15];
    const float* Wp = (const float*)d_in[16];
    const float* bp = (const float*)d_in[17];
    float* out = (float*)d_out;

    char* ws = (char*)d_ws;
    size_t o = 0;
    auto alloc = [&](size_t bytes) {
        void* pp = ws + o;
        o += bytes;
        o = (o + 255) & ~255ull;
        return pp;
    };
    int*      cnt       = (int*)alloc(N_NODES * 4);
    int*      row_start = (int*)alloc((N_NODES + 1) * 4);
    int*      csum      = (int*)alloc(NCHUNK * 4);
    float*    dinv      = (float*)alloc(N_NODES * 4);
    int2*     e_pack    = (int2*)alloc((size_t)(N_EDGES + 8) * 8);
    _Float16* Wt2       = (_Float16*)alloc(HID * HID * 2);
    _Float16* Wt3       = (_Float16*)alloc(HID * HID * 2);
    __half2*  H16       = (__half2*)alloc((size_t)(N_NODES + 64) * HID * 2);
    __half2*  A16       = (__half2*)alloc((size_t)(N_NODES + 64) * HID * 2);
    float*    psum_rep  = (float*)alloc((size_t)NREP * N_GRAPHS * HID * 4);

    k_init<<<512, 256, 0, stream>>>(cnt, psum_rep, W2, W3, Wt2, Wt3, e_pack);
    k_count<<<(N_EDGES + 255) / 256, 256, 0, stream>>>(dst, cnt);
    k_chunksum<<<NCHUNK, 256, 0, stream>>>(cnt, csum, dinv);
    k_scan<<<NCHUNK, 256, 0, stream>>>(cnt, csum, row_start);
    k_scatter<<<(N_EDGES + 255) / 256, 256, 0, stream>>>(src, dst, dinv, row_start,
                                                         cnt, e_pack);
    k_agg5g1<<<(N_NODES * 8 + 255) / 256, 256, 0, stream>>>(x, dinv, row_start, e_pack,
                                                            W1, b1, g1, be1, H16);
    k_fuse2<<<N_NODES / TB, 256, 0, stream>>>((const _Float16*)H16, dinv, row_start,
                                              e_pack, Wt2, b2, g2, be2, (_Float16*)A16);
    k_fuse3<<<N_NODES / TB, 256, 0, stream>>>((const _Float16*)A16, dinv, row_start,
                                              e_pack, Wt3, b3, g3, be3, batch, psum_rep);
    k_final<<<N_GRAPHS, EMB, 0, stream>>>(psum_rep, batch, Wp, bp, out);
}

// Round 5
// 276.913 us; speedup vs baseline: 1.0130x; 1.0130x over previous
//
#include <hip/hip_runtime.h>
#include <hip/hip_fp16.h>

#define N_NODES 50000
#define N_EDGES 600000
#define N_GRAPHS 64
#define IN_D 5
#define HID 128
#define EMB 64

#define CHUNK 512
#define NCHUNK ((N_NODES + CHUNK - 1) / CHUNK)   // 98
#define NREP 16          // psum replication factor (contention spread)
#define NLOC 4           // per-block local graph slots (16 sorted nodes span <=2)
#define TB 16            // nodes per fused agg+gemm tile (50000 = 3125*16, no tail)

typedef _Float16 half8 __attribute__((ext_vector_type(8)));
typedef float float4v __attribute__((ext_vector_type(4)));
typedef float floatx2 __attribute__((ext_vector_type(2)));

// ---------- 1. init: zero everything + fp16-transpose W2/W3 ----------

__global__ __launch_bounds__(256) void k_init(
        int* __restrict__ cnt, float* __restrict__ psum_rep,
        const float* __restrict__ W2, const float* __restrict__ W3,
        _Float16* __restrict__ Wt2, _Float16* __restrict__ Wt3,
        int2* __restrict__ e_pack) {
    int tid = blockIdx.x * blockDim.x + threadIdx.x;
    int nt = gridDim.x * blockDim.x;
    for (int i = tid; i < N_NODES; i += nt) cnt[i] = 0;
    for (int i = tid; i < NREP * N_GRAPHS * HID; i += nt) psum_rep[i] = 0.f;
    if (tid < 8) e_pack[N_EDGES + tid] = make_int2(0, 0);  // safe pad for slot-reads
    for (int i = tid; i < 2 * HID * HID; i += nt) {
        int rem = i & (HID * HID - 1);
        int k = rem & 127, f = rem >> 7;
        if (i < HID * HID) Wt2[rem] = (_Float16)W2[k * HID + f];
        else               Wt3[rem] = (_Float16)W3[k * HID + f];
    }
}

// ---------- 2. degree count ----------

__global__ __launch_bounds__(256) void k_count(
        const int* __restrict__ dst, int* __restrict__ cnt) {
    int e = blockIdx.x * blockDim.x + threadIdx.x;
    if (e < N_EDGES) atomicAdd(&cnt[dst[e]], 1);
}

// ---------- 3. per-chunk sums + dinv ----------

__global__ void k_chunksum(const int* __restrict__ cnt, int* __restrict__ csum,
                           float* __restrict__ dinv) {
    __shared__ int sh[256];
    int b = blockIdx.x, t = threadIdx.x;
    int i0 = b * CHUNK + t, i1 = i0 + 256;
    int v = 0;
    if (i0 < N_NODES) { int c = cnt[i0]; v += c; dinv[i0] = rsqrtf((float)c + 1.0f); }
    if (i1 < N_NODES) { int c = cnt[i1]; v += c; dinv[i1] = rsqrtf((float)c + 1.0f); }
    sh[t] = v; __syncthreads();
    for (int off = 128; off > 0; off >>= 1) {
        if (t < off) sh[t] += sh[t + off];
        __syncthreads();
    }
    if (t == 0) csum[b] = sh[0];
}

// ---------- 4. per-chunk exclusive scan -> row_start ----------

__global__ void k_scan(const int* __restrict__ cnt, const int* __restrict__ csum,
                       int* __restrict__ row_start) {
    __shared__ int ws[4];
    int b = blockIdx.x, t = threadIdx.x;
    int lane = t & 63, w = t >> 6;

    int pre = 0;
    for (int j = lane; j < b; j += 64) pre += csum[j];
    #pragma unroll
    for (int off = 32; off > 0; off >>= 1) pre += __shfl_down(pre, off);
    pre = __shfl(pre, 0);

    int base = b * CHUNK;
    int i0 = base + 2 * t, i1 = i0 + 1;
    int c0 = (i0 < N_NODES) ? cnt[i0] : 0;
    int c1 = (i1 < N_NODES) ? cnt[i1] : 0;
    int v = c0 + c1;
    int s = v;
    #pragma unroll
    for (int off = 1; off < 64; off <<= 1) {
        int u = __shfl_up(s, off);
        if (lane >= off) s += u;
    }
    if (lane == 63) ws[w] = s;
    __syncthreads();
    if (t == 0) {
        int r = 0;
        #pragma unroll
        for (int j = 0; j < 4; ++j) { int xx = ws[j]; ws[j] = r; r += xx; }
    }
    __syncthreads();
    int excl = s - v + ws[w] + pre;
    if (i0 < N_NODES) row_start[i0] = excl;
    if (i1 < N_NODES) row_start[i1] = excl + c0;
    if (b == 0 && t == 0) row_start[N_NODES] = N_EDGES;
}

// ---------- 5. scatter edges into CSR order (cnt reused as fill via atomicSub) ----------

__global__ __launch_bounds__(256) void k_scatter(
        const int* __restrict__ src, const int* __restrict__ dst,
        const float* __restrict__ dinv, const int* __restrict__ row_start,
        int* __restrict__ cnt, int2* __restrict__ e_pack) {
    int e = blockIdx.x * blockDim.x + threadIdx.x;
    if (e >= N_EDGES) return;
    int d = dst[e];
    int pos = row_start[d] + atomicSub(&cnt[d], 1) - 1;
    int s = src[e];
    e_pack[pos] = make_int2(s, __float_as_int(dinv[s]));
}

// ---------- 6. fused layer 1: agg(x) + gemm1 + bn + relu -> H8 (fp8 e4m3) ----------

__global__ __launch_bounds__(256) void k_agg5g1(
        const float* __restrict__ x, const float* __restrict__ dinv,
        const int* __restrict__ row_start, const int2* __restrict__ e_pack,
        const float* __restrict__ W1, const float* __restrict__ b1,
        const float* __restrict__ g1, const float* __restrict__ be1,
        unsigned int* __restrict__ H8) {
    int gid = blockIdx.x * blockDim.x + threadIdx.x;
    int i = gid >> 3, k = gid & 7;
    if (i >= N_NODES) return;
    float acc = 0.f;
    if (k < IN_D) {
        int beg = row_start[i], end = row_start[i + 1];
        int e = beg;
        for (; e + 3 < end; e += 4) {
            int2 p0 = e_pack[e];
            int2 p1 = e_pack[e + 1];
            int2 p2 = e_pack[e + 2];
            int2 p3 = e_pack[e + 3];
            float x0 = x[p0.x * IN_D + k];
            float x1 = x[p1.x * IN_D + k];
            float x2 = x[p2.x * IN_D + k];
            float x3 = x[p3.x * IN_D + k];
            acc = fmaf(__int_as_float(p0.y), x0, acc);
            acc = fmaf(__int_as_float(p1.y), x1, acc);
            acc = fmaf(__int_as_float(p2.y), x2, acc);
            acc = fmaf(__int_as_float(p3.y), x3, acc);
        }
        for (; e < end; ++e) {
            int2 p = e_pack[e];
            acc = fmaf(__int_as_float(p.y), x[p.x * IN_D + k], acc);
        }
        float di = dinv[i];
        acc = di * (acc + di * x[i * IN_D + k]);
    }
    int lane = threadIdx.x & 63;
    int base = lane & ~7;
    float a0 = __shfl(acc, base + 0);
    float a1 = __shfl(acc, base + 1);
    float a2 = __shfl(acc, base + 2);
    float a3 = __shfl(acc, base + 3);
    float a4 = __shfl(acc, base + 4);
    const float rs = rsqrtf(1.0f + 1e-5f);
    int f0 = k * 16;
    float vv[16];
    #pragma unroll
    for (int u = 0; u < 8; ++u) {
        int fa = f0 + u * 2, fb = fa + 1;
        float va = b1[fa], vb = b1[fb];
        va = fmaf(a0, W1[0 * HID + fa], va); vb = fmaf(a0, W1[0 * HID + fb], vb);
        va = fmaf(a1, W1[1 * HID + fa], va); vb = fmaf(a1, W1[1 * HID + fb], vb);
        va = fmaf(a2, W1[2 * HID + fa], va); vb = fmaf(a2, W1[2 * HID + fb], vb);
        va = fmaf(a3, W1[3 * HID + fa], va); vb = fmaf(a3, W1[3 * HID + fb], vb);
        va = fmaf(a4, W1[4 * HID + fa], va); vb = fmaf(a4, W1[4 * HID + fb], vb);
        va = fmaf(va, g1[fa] * rs, be1[fa]);
        vb = fmaf(vb, g1[fb] * rs, be1[fb]);
        vv[u * 2]     = va > 0.f ? va : 0.f;
        vv[u * 2 + 1] = vb > 0.f ? vb : 0.f;
    }
    unsigned int pk[4];
    #pragma unroll
    for (int q = 0; q < 4; ++q) {
        int r = __builtin_amdgcn_cvt_pk_fp8_f32(vv[4 * q + 0], vv[4 * q + 1], 0, false);
        r = __builtin_amdgcn_cvt_pk_fp8_f32(vv[4 * q + 2], vv[4 * q + 3], r, true);
        pk[q] = (unsigned int)r;
    }
    ((uint4*)(H8 + (size_t)i * 32))[k] = make_uint4(pk[0], pk[1], pk[2], pk[3]);
}

// ---------- fp8 multi-edge agg: one gather inst fetches 8 edge-rows ----------
// lane = slot8*8 + q8: slot8 (0..7) picks an edge, q8 picks 16 fp8 features
// (16B). Per 8 edges: 1 e_pack inst + 1 gather inst (2 lines/edge). Cross-slot
// reduce = 3 shfl_xor per value per NODE. Masked slots read in-bounds pad
// (weight forced 0). Output re-expanded to fp16 in the LDS A-row (MFMA input).

__device__ __forceinline__ void agg_node_fp8(
        const unsigned int* __restrict__ H8, const float* __restrict__ dinv,
        const int* __restrict__ row_start, const int2* __restrict__ e_pack,
        int n, int slot8, int q8, _Float16* __restrict__ asrow) {
    float acc[16];
    #pragma unroll
    for (int j = 0; j < 16; ++j) acc[j] = 0.f;
    int beg = row_start[n], end = row_start[n + 1];
    for (int e = beg; e < end; e += 8) {
        int2 pe = e_pack[e + slot8];
        float fw = (e + slot8 < end) ? __int_as_float(pe.y) : 0.f;
        uint4 g = ((const uint4*)(H8 + (size_t)pe.x * 32))[q8];
        unsigned int gw[4] = {g.x, g.y, g.z, g.w};
        #pragma unroll
        for (int q = 0; q < 4; ++q) {
            floatx2 lo = __builtin_amdgcn_cvt_pk_f32_fp8(gw[q], false);
            floatx2 hi = __builtin_amdgcn_cvt_pk_f32_fp8(gw[q], true);
            acc[4 * q + 0] = fmaf(fw, lo[0], acc[4 * q + 0]);
            acc[4 * q + 1] = fmaf(fw, lo[1], acc[4 * q + 1]);
            acc[4 * q + 2] = fmaf(fw, hi[0], acc[4 * q + 2]);
            acc[4 * q + 3] = fmaf(fw, hi[1], acc[4 * q + 3]);
        }
    }
    #pragma unroll
    for (int j = 0; j < 16; ++j) {
        float a = acc[j];
        a += __shfl_xor(a, 8);
        a += __shfl_xor(a, 16);
        a += __shfl_xor(a, 32);
        acc[j] = a;
    }
    if (slot8 == 0) {
        float di = dinv[n];
        uint4 s = ((const uint4*)(H8 + (size_t)n * 32))[q8];
        unsigned int sw[4] = {s.x, s.y, s.z, s.w};
        float sv[16];
        #pragma unroll
        for (int q = 0; q < 4; ++q) {
            floatx2 lo = __builtin_amdgcn_cvt_pk_f32_fp8(sw[q], false);
            floatx2 hi = __builtin_amdgcn_cvt_pk_f32_fp8(sw[q], true);
            sv[4 * q + 0] = lo[0]; sv[4 * q + 1] = lo[1];
            sv[4 * q + 2] = hi[0]; sv[4 * q + 3] = hi[1];
        }
        half8 o0, o1;
        #pragma unroll
        for (int j = 0; j < 8; ++j)
            o0[j] = (_Float16)(di * fmaf(di, sv[j], acc[j]));
        #pragma unroll
        for (int j = 0; j < 8; ++j)
            o1[j] = (_Float16)(di * fmaf(di, sv[j + 8], acc[j + 8]));
        *(half8*)(asrow + q8 * 16) = o0;
        *(half8*)(asrow + q8 * 16 + 8) = o1;
    }
}

// ---------- 7. fused layer 2: fp8 agg -> LDS(fp16) -> MFMA + bn + relu -> fp8 ----------

__global__ __launch_bounds__(256) void k_fuse2(
        const unsigned int* __restrict__ Hin, const float* __restrict__ dinv,
        const int* __restrict__ row_start, const int2* __restrict__ e_pack,
        const _Float16* __restrict__ Wt,
        const float* __restrict__ bb, const float* __restrict__ gg,
        const float* __restrict__ bee, unsigned char* __restrict__ out8) {
    __shared__ __align__(16) _Float16 As[TB][136];
    int t = threadIdx.x;
    int w = t >> 6, lane = t & 63;
    int slot8 = lane >> 3, q8 = lane & 7;
    int nb = blockIdx.x * TB;

    #pragma unroll 1
    for (int i = 0; i < 4; ++i)
        agg_node_fp8(Hin, dinv, row_start, e_pack, nb + w * 4 + i,
                     slot8, q8, &As[w * 4 + i][0]);
    __syncthreads();

    int quad = lane >> 4, r16 = lane & 15;
    half8 a[4];
    #pragma unroll
    for (int kb = 0; kb < 4; ++kb)
        a[kb] = *(const half8*)&As[r16][(kb * 4 + quad) * 8];
    const float rs = rsqrtf(1.0f + 1e-5f);
    #pragma unroll
    for (int fi = 0; fi < 2; ++fi) {
        int f = (w * 2 + fi) * 16 + r16;
        const half8* Brow = (const half8*)(Wt + (size_t)f * 128);
        float4v acc = {0.f, 0.f, 0.f, 0.f};
        #pragma unroll
        for (int kb = 0; kb < 4; ++kb)
            acc = __builtin_amdgcn_mfma_f32_16x16x32_f16(a[kb], Brow[kb * 4 + quad],
                                                         acc, 0, 0, 0);
        float b0 = bb[f], gf = gg[f] * rs, e0 = bee[f];
        #pragma unroll
        for (int rr = 0; rr < 4; ++rr) {
            float v = fmaf(acc[rr] + b0, gf, e0);
            v = v > 0.f ? v : 0.f;
            int p = __builtin_amdgcn_cvt_pk_fp8_f32(v, 0.f, 0, false);
            out8[(size_t)(nb + quad * 4 + rr) * 128 + f] = (unsigned char)(p & 0xff);
        }
    }
}

// ---------- 8. fused layer 3: fp8 agg -> MFMA + bn + relu + mean-pool ----------

__global__ __launch_bounds__(256) void k_fuse3(
        const unsigned int* __restrict__ Hin, const float* __restrict__ dinv,
        const int* __restrict__ row_start, const int2* __restrict__ e_pack,
        const _Float16* __restrict__ Wt,
        const float* __restrict__ bb, const float* __restrict__ gg,
        const float* __restrict__ bee, const int* __restrict__ batch,
        float* __restrict__ psum_rep) {
    __shared__ __align__(16) _Float16 As[TB][136];
    __shared__ float sh_pool[NLOC][HID];
    int t = threadIdx.x;
    int w = t >> 6, lane = t & 63;
    int slot8 = lane >> 3, q8 = lane & 7;
    int blk = (int)blockIdx.x;
    int nb = blk * TB;

    for (int i = t; i < NLOC * HID; i += 256) ((float*)sh_pool)[i] = 0.f;

    #pragma unroll 1
    for (int i = 0; i < 4; ++i)
        agg_node_fp8(Hin, dinv, row_start, e_pack, nb + w * 4 + i,
                     slot8, q8, &As[w * 4 + i][0]);

    int quad = lane >> 4, r16 = lane & 15;
    int g0 = batch[nb];
    int gi4[4];
    #pragma unroll
    for (int rr = 0; rr < 4; ++rr) gi4[rr] = batch[nb + quad * 4 + rr];
    __syncthreads();

    half8 a[4];
    #pragma unroll
    for (int kb = 0; kb < 4; ++kb)
        a[kb] = *(const half8*)&As[r16][(kb * 4 + quad) * 8];
    float* rep = psum_rep + (size_t)(blk & (NREP - 1)) * N_GRAPHS * HID;
    const float rs = rsqrtf(1.0f + 1e-5f);
    #pragma unroll
    for (int fi = 0; fi < 2; ++fi) {
        int f = (w * 2 + fi) * 16 + r16;
        const half8* Brow = (const half8*)(Wt + (size_t)f * 128);
        float4v acc = {0.f, 0.f, 0.f, 0.f};
        #pragma unroll
        for (int kb = 0; kb < 4; ++kb)
            acc = __builtin_amdgcn_mfma_f32_16x16x32_f16(a[kb], Brow[kb * 4 + quad],
                                                         acc, 0, 0, 0);
        float b0 = bb[f], gf = gg[f] * rs, e0 = bee[f];
        float partial = 0.f;
        int cur = -1;
        #pragma unroll
        for (int rr = 0; rr < 4; ++rr) {
            float v = fmaf(acc[rr] + b0, gf, e0);
            v = v > 0.f ? v : 0.f;
            int gi = gi4[rr];
            if (gi != cur) {
                if (cur >= 0) {
                    int idx = cur - g0;
                    if (idx < NLOC) atomicAdd(&sh_pool[idx][f], partial);
                    else            atomicAdd(&rep[cur * HID + f], partial);
                }
                partial = 0.f; cur = gi;
            }
            partial += v;
        }
        if (cur >= 0) {
            int idx = cur - g0;
            if (idx < NLOC) atomicAdd(&sh_pool[idx][f], partial);
            else            atomicAdd(&rep[cur * HID + f], partial);
        }
    }
    __syncthreads();
    // flush LDS partials: one replicated global atomic per (graph,f) present
    for (int i = t; i < NLOC * HID; i += 256) {
        int idx = i >> 7, ff = i & 127;
        float v = sh_pool[idx][ff];
        int g = g0 + idx;
        if (v != 0.f && g < N_GRAPHS) atomicAdd(&rep[g * HID + ff], v);
    }
}

// ---------- 9. projection (+ graph counts via binary search, no atomics) ----------

__device__ __forceinline__ int lower_bound_batch(const int* __restrict__ batch, int val) {
    int lo = 0, hi = N_NODES;
    while (lo < hi) {
        int mid = (lo + hi) >> 1;
        if (batch[mid] < val) lo = mid + 1;
        else hi = mid;
    }
    return lo;
}

__global__ void k_final(const float* __restrict__ psum_rep, const int* __restrict__ batch,
                        const float* __restrict__ Wp, const float* __restrict__ bp,
                        float* __restrict__ out) {
    __shared__ float s_p[HID];
    int gi = blockIdx.x, e = threadIdx.x;   // 64 threads
    for (int f = e; f < HID; f += EMB) {
        float v = 0.f;
        #pragma unroll
        for (int r = 0; r < NREP; ++r)
            v += psum_rep[(size_t)r * N_GRAPHS * HID + gi * HID + f];
        s_p[f] = v;
    }
    int lane = e & 63;
    int r = 0;
    if (lane < 2) r = lower_bound_batch(batch, gi + lane);
    int c0 = __shfl(r, 0), c1 = __shfl(r, 1);
    float inv = 1.0f / fmaxf((float)(c1 - c0), 1.0f);
    __syncthreads();
    float acc = bp[e];
    #pragma unroll 8
    for (int f = 0; f < HID; ++f)
        acc = fmaf(s_p[f] * inv, Wp[f * EMB + e], acc);
    out[gi * EMB + e] = acc;
}

// ---------- launcher ----------

extern "C" void kernel_launch(void* const* d_in, const int* in_sizes, int n_in,
                              void* d_out, int out_size, void* d_ws, size_t ws_size,
                              hipStream_t stream) {
    const float* x   = (const float*)d_in[0];
    const int*   src = (const int*)d_in[1];
    const int*   dst = (const int*)d_in[2];
    const int* batch = (const int*)d_in[3];
    const float* W1 = (const float*)d_in[4];
    const float* b1 = (const float*)d_in[5];
    const float* W2 = (const float*)d_in[6];
    const float* b2 = (const float*)d_in[7];
    const float* W3 = (const float*)d_in[8];
    const float* b3 = (const float*)d_in[9];
    const float* g1 = (const float*)d_in[10];
    const float* be1 = (const float*)d_in[11];
    const float* g2 = (const float*)d_in[12];
    const float* be2 = (const float*)d_in[13];
    const float* g3 = (const float*)d_in[14];
    const float* be3 = (const float*)d_in[15];
    const float* Wp = (const float*)d_in[16];
    const float* bp = (const float*)d_in[17];
    float* out = (float*)d_out;

    char* ws = (char*)d_ws;
    size_t o = 0;
    auto alloc = [&](size_t bytes) {
        void* pp = ws + o;
        o += bytes;
        o = (o + 255) & ~255ull;
        return pp;
    };
    int*      cnt       = (int*)alloc(N_NODES * 4);
    int*      row_start = (int*)alloc((N_NODES + 1) * 4);
    int*      csum      = (int*)alloc(NCHUNK * 4);
    float*    dinv      = (float*)alloc(N_NODES * 4);
    int2*     e_pack    = (int2*)alloc((size_t)(N_EDGES + 8) * 8);
    _Float16* Wt2       = (_Float16*)alloc(HID * HID * 2);
    _Float16* Wt3       = (_Float16*)alloc(HID * HID * 2);
    unsigned int* H8a   = (unsigned int*)alloc((size_t)N_NODES * HID);  // fp8 rows
    unsigned int* H8b   = (unsigned int*)alloc((size_t)N_NODES * HID);
    float*    psum_rep  = (float*)alloc((size_t)NREP * N_GRAPHS * HID * 4);

    k_init<<<512, 256, 0, stream>>>(cnt, psum_rep, W2, W3, Wt2, Wt3, e_pack);
    k_count<<<(N_EDGES + 255) / 256, 256, 0, stream>>>(dst, cnt);
    k_chunksum<<<NCHUNK, 256, 0, stream>>>(cnt, csum, dinv);
    k_scan<<<NCHUNK, 256, 0, stream>>>(cnt, csum, row_start);
    k_scatter<<<(N_EDGES + 255) / 256, 256, 0, stream>>>(src, dst, dinv, row_start,
                                                         cnt, e_pack);
    k_agg5g1<<<(N_NODES * 8 + 255) / 256, 256, 0, stream>>>(x, dinv, row_start, e_pack,
                                                            W1, b1, g1, be1, H8a);
    k_fuse2<<<N_NODES / TB, 256, 0, stream>>>(H8a, dinv, row_start, e_pack, Wt2,
                                              b2, g2, be2, (unsigned char*)H8b);
    k_fuse3<<<N_NODES / TB, 256, 0, stream>>>(H8b, dinv, row_start, e_pack, Wt3,
                                              b3, g3, be3, batch, psum_rep);
    k_final<<<N_GRAPHS, EMB, 0, stream>>>(psum_rep, batch, Wp, bp, out);
}

// Round 6
// 270.606 us; speedup vs baseline: 1.0366x; 1.0233x over previous
//
#include <hip/hip_runtime.h>
#include <hip/hip_fp16.h>

#define N_NODES 50000
#define N_EDGES 600000
#define N_GRAPHS 64
#define IN_D 5
#define HID 128
#define EMB 64

#define CHUNK 512
#define NCHUNK ((N_NODES + CHUNK - 1) / CHUNK)   // 98
#define NREP 16          // psum replication factor (contention spread)
#define NLOC 4           // per-block local graph slots (16 sorted nodes span <=2)
#define TB 16            // nodes per fused agg+gemm tile (50000 = 3125*16, no tail)
#define ECAP 1024        // LDS edge-descriptor cache entries (block avg ~192)

typedef _Float16 half8 __attribute__((ext_vector_type(8)));
typedef float float4v __attribute__((ext_vector_type(4)));
typedef float floatx2 __attribute__((ext_vector_type(2)));

// ---------- 1. init: zero everything + fp16-transpose W2/W3 + pad x ----------

__global__ __launch_bounds__(256) void k_init(
        int* __restrict__ cnt, float* __restrict__ psum_rep,
        const float* __restrict__ W2, const float* __restrict__ W3,
        _Float16* __restrict__ Wt2, _Float16* __restrict__ Wt3,
        int2* __restrict__ e_pack,
        const float* __restrict__ x, float* __restrict__ xp) {
    int tid = blockIdx.x * blockDim.x + threadIdx.x;
    int nt = gridDim.x * blockDim.x;
    for (int i = tid; i < N_NODES; i += nt) cnt[i] = 0;
    for (int i = tid; i < NREP * N_GRAPHS * HID; i += nt) psum_rep[i] = 0.f;
    if (tid < 8) e_pack[N_EDGES + tid] = make_int2(0, 0);  // safe pad for slot-reads
    for (int i = tid; i < N_NODES * 8; i += nt) {
        int f = i & 7, n = i >> 3;
        xp[i] = (f < IN_D) ? x[n * IN_D + f] : 0.f;
    }
    for (int i = tid; i < 2 * HID * HID; i += nt) {
        int rem = i & (HID * HID - 1);
        int k = rem & 127, f = rem >> 7;
        if (i < HID * HID) Wt2[rem] = (_Float16)W2[k * HID + f];
        else               Wt3[rem] = (_Float16)W3[k * HID + f];
    }
}

// ---------- 2. degree count ----------

__global__ __launch_bounds__(256) void k_count(
        const int* __restrict__ dst, int* __restrict__ cnt) {
    int e = blockIdx.x * blockDim.x + threadIdx.x;
    if (e < N_EDGES) atomicAdd(&cnt[dst[e]], 1);
}

// ---------- 3. per-chunk sums + dinv ----------

__global__ void k_chunksum(const int* __restrict__ cnt, int* __restrict__ csum,
                           float* __restrict__ dinv) {
    __shared__ int sh[256];
    int b = blockIdx.x, t = threadIdx.x;
    int i0 = b * CHUNK + t, i1 = i0 + 256;
    int v = 0;
    if (i0 < N_NODES) { int c = cnt[i0]; v += c; dinv[i0] = rsqrtf((float)c + 1.0f); }
    if (i1 < N_NODES) { int c = cnt[i1]; v += c; dinv[i1] = rsqrtf((float)c + 1.0f); }
    sh[t] = v; __syncthreads();
    for (int off = 128; off > 0; off >>= 1) {
        if (t < off) sh[t] += sh[t + off];
        __syncthreads();
    }
    if (t == 0) csum[b] = sh[0];
}

// ---------- 4. per-chunk exclusive scan -> row_start ----------

__global__ void k_scan(const int* __restrict__ cnt, const int* __restrict__ csum,
                       int* __restrict__ row_start) {
    __shared__ int ws[4];
    int b = blockIdx.x, t = threadIdx.x;
    int lane = t & 63, w = t >> 6;

    int pre = 0;
    for (int j = lane; j < b; j += 64) pre += csum[j];
    #pragma unroll
    for (int off = 32; off > 0; off >>= 1) pre += __shfl_down(pre, off);
    pre = __shfl(pre, 0);

    int base = b * CHUNK;
    int i0 = base + 2 * t, i1 = i0 + 1;
    int c0 = (i0 < N_NODES) ? cnt[i0] : 0;
    int c1 = (i1 < N_NODES) ? cnt[i1] : 0;
    int v = c0 + c1;
    int s = v;
    #pragma unroll
    for (int off = 1; off < 64; off <<= 1) {
        int u = __shfl_up(s, off);
        if (lane >= off) s += u;
    }
    if (lane == 63) ws[w] = s;
    __syncthreads();
    if (t == 0) {
        int r = 0;
        #pragma unroll
        for (int j = 0; j < 4; ++j) { int xx = ws[j]; ws[j] = r; r += xx; }
    }
    __syncthreads();
    int excl = s - v + ws[w] + pre;
    if (i0 < N_NODES) row_start[i0] = excl;
    if (i1 < N_NODES) row_start[i1] = excl + c0;
    if (b == 0 && t == 0) row_start[N_NODES] = N_EDGES;
}

// ---------- 5. scatter edges into CSR order (cnt reused as fill via atomicSub) ----------

__global__ __launch_bounds__(256) void k_scatter(
        const int* __restrict__ src, const int* __restrict__ dst,
        const float* __restrict__ dinv, const int* __restrict__ row_start,
        int* __restrict__ cnt, int2* __restrict__ e_pack) {
    int e = blockIdx.x * blockDim.x + threadIdx.x;
    if (e >= N_EDGES) return;
    int d = dst[e];
    int pos = row_start[d] + atomicSub(&cnt[d], 1) - 1;
    int s = src[e];
    e_pack[pos] = make_int2(s, __float_as_int(dinv[s]));
}

// ---------- 6. fused layer 1: slot-gather agg(xp) + gemm1 + bn + relu -> fp8 H ----------
// lane = slot8*8 + q8: slot8 picks an edge, q8 a feature (xp padded to 8 f32).
// e_pack descriptors staged in LDS (one coalesced burst) so the hot loop has a
// single global hop (the xp gather, L2-resident 1.6MB table). GEMM1 epilogue
// fused with hoisted W1 columns; fp8 output written 2B/lane contiguous.

__global__ __launch_bounds__(256) void k_agg1(
        const float* __restrict__ xp, const float* __restrict__ dinv,
        const int* __restrict__ row_start, const int2* __restrict__ e_pack,
        const float* __restrict__ W1, const float* __restrict__ b1,
        const float* __restrict__ g1, const float* __restrict__ be1,
        unsigned short* __restrict__ H8u) {
    __shared__ int2 eL[ECAP];
    int t = threadIdx.x;
    int w = t >> 6, lane = t & 63;
    int slot8 = lane >> 3, q8 = lane & 7;
    int nb = blockIdx.x * TB;

    int E0 = row_start[nb], E1 = row_start[nb + TB];
    int cntL = E1 - E0 + 8; if (cntL > ECAP) cntL = ECAP;
    for (int i = t; i < cntL; i += 256) eL[i] = e_pack[E0 + i];
    __syncthreads();

    const float rs = rsqrtf(1.0f + 1e-5f);
    int fa = lane * 2, fb = fa + 1;
    float w1a[IN_D], w1b[IN_D];
    #pragma unroll
    for (int k = 0; k < IN_D; ++k) {
        w1a[k] = W1[k * HID + fa];
        w1b[k] = W1[k * HID + fb];
    }
    float b1a = b1[fa], b1b = b1[fb];
    float g1a = g1[fa] * rs, g1b = g1[fb] * rs;
    float e1a = be1[fa], e1b = be1[fb];

    #pragma unroll 1
    for (int i = 0; i < 4; ++i) {
        int n = nb + w * 4 + i;
        int beg = row_start[n], end = row_start[n + 1];
        float acc = 0.f;
        for (int e = beg; e < end; e += 8) {
            int eo = e + slot8 - E0;
            int2 pe;
            if (eo < cntL) pe = eL[eo];
            else           pe = e_pack[e + slot8];
            float fw = (e + slot8 < end) ? __int_as_float(pe.y) : 0.f;
            float g = xp[(size_t)pe.x * 8 + q8];
            acc = fmaf(fw, g, acc);
        }
        acc += __shfl_xor(acc, 8);
        acc += __shfl_xor(acc, 16);
        acc += __shfl_xor(acc, 32);
        float di = dinv[n];
        float av = di * fmaf(di, xp[(size_t)n * 8 + q8], acc);
        float a0 = __shfl(av, 0), a1 = __shfl(av, 1), a2 = __shfl(av, 2),
              a3 = __shfl(av, 3), a4 = __shfl(av, 4);
        float va = b1a, vb = b1b;
        va = fmaf(a0, w1a[0], va); vb = fmaf(a0, w1b[0], vb);
        va = fmaf(a1, w1a[1], va); vb = fmaf(a1, w1b[1], vb);
        va = fmaf(a2, w1a[2], va); vb = fmaf(a2, w1b[2], vb);
        va = fmaf(a3, w1a[3], va); vb = fmaf(a3, w1b[3], vb);
        va = fmaf(a4, w1a[4], va); vb = fmaf(a4, w1b[4], vb);
        va = fmaf(va, g1a, e1a);
        vb = fmaf(vb, g1b, e1b);
        va = va > 0.f ? va : 0.f;
        vb = vb > 0.f ? vb : 0.f;
        int p = __builtin_amdgcn_cvt_pk_fp8_f32(va, vb, 0, false);
        H8u[(size_t)n * 64 + lane] = (unsigned short)(p & 0xffff);
    }
}

// ---------- fp8 multi-edge agg (e_pack from LDS): 1 gather inst = 8 edge-rows ----------

__device__ __forceinline__ void agg_node_fp8(
        const unsigned int* __restrict__ H8, const float* __restrict__ dinv,
        const int* __restrict__ row_start, const int2* __restrict__ e_pack,
        const int2* __restrict__ eL, int E0, int cntL,
        int n, int slot8, int q8, _Float16* __restrict__ asrow) {
    float acc[16];
    #pragma unroll
    for (int j = 0; j < 16; ++j) acc[j] = 0.f;
    int beg = row_start[n], end = row_start[n + 1];
    for (int e = beg; e < end; e += 8) {
        int eo = e + slot8 - E0;
        int2 pe;
        if (eo < cntL) pe = eL[eo];
        else           pe = e_pack[e + slot8];
        float fw = (e + slot8 < end) ? __int_as_float(pe.y) : 0.f;
        uint4 g = ((const uint4*)(H8 + (size_t)pe.x * 32))[q8];
        unsigned int gw[4] = {g.x, g.y, g.z, g.w};
        #pragma unroll
        for (int q = 0; q < 4; ++q) {
            floatx2 lo = __builtin_amdgcn_cvt_pk_f32_fp8(gw[q], false);
            floatx2 hi = __builtin_amdgcn_cvt_pk_f32_fp8(gw[q], true);
            acc[4 * q + 0] = fmaf(fw, lo[0], acc[4 * q + 0]);
            acc[4 * q + 1] = fmaf(fw, lo[1], acc[4 * q + 1]);
            acc[4 * q + 2] = fmaf(fw, hi[0], acc[4 * q + 2]);
            acc[4 * q + 3] = fmaf(fw, hi[1], acc[4 * q + 3]);
        }
    }
    #pragma unroll
    for (int j = 0; j < 16; ++j) {
        float a = acc[j];
        a += __shfl_xor(a, 8);
        a += __shfl_xor(a, 16);
        a += __shfl_xor(a, 32);
        acc[j] = a;
    }
    if (slot8 == 0) {
        float di = dinv[n];
        uint4 s = ((const uint4*)(H8 + (size_t)n * 32))[q8];
        unsigned int sw[4] = {s.x, s.y, s.z, s.w};
        float sv[16];
        #pragma unroll
        for (int q = 0; q < 4; ++q) {
            floatx2 lo = __builtin_amdgcn_cvt_pk_f32_fp8(sw[q], false);
            floatx2 hi = __builtin_amdgcn_cvt_pk_f32_fp8(sw[q], true);
            sv[4 * q + 0] = lo[0]; sv[4 * q + 1] = lo[1];
            sv[4 * q + 2] = hi[0]; sv[4 * q + 3] = hi[1];
        }
        half8 o0, o1;
        #pragma unroll
        for (int j = 0; j < 8; ++j)
            o0[j] = (_Float16)(di * fmaf(di, sv[j], acc[j]));
        #pragma unroll
        for (int j = 0; j < 8; ++j)
            o1[j] = (_Float16)(di * fmaf(di, sv[j + 8], acc[j + 8]));
        *(half8*)(asrow + q8 * 16) = o0;
        *(half8*)(asrow + q8 * 16 + 8) = o1;
    }
}

// ---------- 7. fused layer 2: fp8 agg -> LDS(fp16) -> MFMA + bn + relu -> fp8 ----------

__global__ __launch_bounds__(256) void k_fuse2(
        const unsigned int* __restrict__ Hin, const float* __restrict__ dinv,
        const int* __restrict__ row_start, const int2* __restrict__ e_pack,
        const _Float16* __restrict__ Wt,
        const float* __restrict__ bb, const float* __restrict__ gg,
        const float* __restrict__ bee, unsigned char* __restrict__ out8) {
    __shared__ __align__(16) _Float16 As[TB][136];
    __shared__ int2 eL[ECAP];
    int t = threadIdx.x;
    int w = t >> 6, lane = t & 63;
    int slot8 = lane >> 3, q8 = lane & 7;
    int nb = blockIdx.x * TB;

    int E0 = row_start[nb], E1 = row_start[nb + TB];
    int cntL = E1 - E0 + 8; if (cntL > ECAP) cntL = ECAP;
    for (int i = t; i < cntL; i += 256) eL[i] = e_pack[E0 + i];
    __syncthreads();

    #pragma unroll 1
    for (int i = 0; i < 4; ++i)
        agg_node_fp8(Hin, dinv, row_start, e_pack, eL, E0, cntL,
                     nb + w * 4 + i, slot8, q8, &As[w * 4 + i][0]);
    __syncthreads();

    int quad = lane >> 4, r16 = lane & 15;
    half8 a[4];
    #pragma unroll
    for (int kb = 0; kb < 4; ++kb)
        a[kb] = *(const half8*)&As[r16][(kb * 4 + quad) * 8];
    const float rs = rsqrtf(1.0f + 1e-5f);
    #pragma unroll
    for (int fi = 0; fi < 2; ++fi) {
        int f = (w * 2 + fi) * 16 + r16;
        const half8* Brow = (const half8*)(Wt + (size_t)f * 128);
        float4v acc = {0.f, 0.f, 0.f, 0.f};
        #pragma unroll
        for (int kb = 0; kb < 4; ++kb)
            acc = __builtin_amdgcn_mfma_f32_16x16x32_f16(a[kb], Brow[kb * 4 + quad],
                                                         acc, 0, 0, 0);
        float b0 = bb[f], gf = gg[f] * rs, e0 = bee[f];
        #pragma unroll
        for (int rr = 0; rr < 4; ++rr) {
            float v = fmaf(acc[rr] + b0, gf, e0);
            v = v > 0.f ? v : 0.f;
            int p = __builtin_amdgcn_cvt_pk_fp8_f32(v, 0.f, 0, false);
            out8[(size_t)(nb + quad * 4 + rr) * 128 + f] = (unsigned char)(p & 0xff);
        }
    }
}

// ---------- 8. fused layer 3: fp8 agg -> MFMA + bn + relu + mean-pool ----------

__global__ __launch_bounds__(256) void k_fuse3(
        const unsigned int* __restrict__ Hin, const float* __restrict__ dinv,
        const int* __restrict__ row_start, const int2* __restrict__ e_pack,
        const _Float16* __restrict__ Wt,
        const float* __restrict__ bb, const float* __restrict__ gg,
        const float* __restrict__ bee, const int* __restrict__ batch,
        float* __restrict__ psum_rep) {
    __shared__ __align__(16) _Float16 As[TB][136];
    __shared__ int2 eL[ECAP];
    __shared__ float sh_pool[NLOC][HID];
    int t = threadIdx.x;
    int w = t >> 6, lane = t & 63;
    int slot8 = lane >> 3, q8 = lane & 7;
    int blk = (int)blockIdx.x;
    int nb = blk * TB;

    for (int i = t; i < NLOC * HID; i += 256) ((float*)sh_pool)[i] = 0.f;
    int E0 = row_start[nb], E1 = row_start[nb + TB];
    int cntL = E1 - E0 + 8; if (cntL > ECAP) cntL = ECAP;
    for (int i = t; i < cntL; i += 256) eL[i] = e_pack[E0 + i];
    __syncthreads();

    #pragma unroll 1
    for (int i = 0; i < 4; ++i)
        agg_node_fp8(Hin, dinv, row_start, e_pack, eL, E0, cntL,
                     nb + w * 4 + i, slot8, q8, &As[w * 4 + i][0]);

    int quad = lane >> 4, r16 = lane & 15;
    int g0 = batch[nb];
    int gi4[4];
    #pragma unroll
    for (int rr = 0; rr < 4; ++rr) gi4[rr] = batch[nb + quad * 4 + rr];
    __syncthreads();

    half8 a[4];
    #pragma unroll
    for (int kb = 0; kb < 4; ++kb)
        a[kb] = *(const half8*)&As[r16][(kb * 4 + quad) * 8];
    float* rep = psum_rep + (size_t)(blk & (NREP - 1)) * N_GRAPHS * HID;
    const float rs = rsqrtf(1.0f + 1e-5f);
    #pragma unroll
    for (int fi = 0; fi < 2; ++fi) {
        int f = (w * 2 + fi) * 16 + r16;
        const half8* Brow = (const half8*)(Wt + (size_t)f * 128);
        float4v acc = {0.f, 0.f, 0.f, 0.f};
        #pragma unroll
        for (int kb = 0; kb < 4; ++kb)
            acc = __builtin_amdgcn_mfma_f32_16x16x32_f16(a[kb], Brow[kb * 4 + quad],
                                                         acc, 0, 0, 0);
        float b0 = bb[f], gf = gg[f] * rs, e0 = bee[f];
        float partial = 0.f;
        int cur = -1;
        #pragma unroll
        for (int rr = 0; rr < 4; ++rr) {
            float v = fmaf(acc[rr] + b0, gf, e0);
            v = v > 0.f ? v : 0.f;
            int gi = gi4[rr];
            if (gi != cur) {
                if (cur >= 0) {
                    int idx = cur - g0;
                    if (idx < NLOC) atomicAdd(&sh_pool[idx][f], partial);
                    else            atomicAdd(&rep[cur * HID + f], partial);
                }
                partial = 0.f; cur = gi;
            }
            partial += v;
        }
        if (cur >= 0) {
            int idx = cur - g0;
            if (idx < NLOC) atomicAdd(&sh_pool[idx][f], partial);
            else            atomicAdd(&rep[cur * HID + f], partial);
        }
    }
    __syncthreads();
    // flush LDS partials: one replicated global atomic per (graph,f) present
    for (int i = t; i < NLOC * HID; i += 256) {
        int idx = i >> 7, ff = i & 127;
        float v = sh_pool[idx][ff];
        int g = g0 + idx;
        if (v != 0.f && g < N_GRAPHS) atomicAdd(&rep[g * HID + ff], v);
    }
}

// ---------- 9. projection (+ graph counts via binary search, no atomics) ----------

__device__ __forceinline__ int lower_bound_batch(const int* __restrict__ batch, int val) {
    int lo = 0, hi = N_NODES;
    while (lo < hi) {
        int mid = (lo + hi) >> 1;
        if (batch[mid] < val) lo = mid + 1;
        else hi = mid;
    }
    return lo;
}

__global__ void k_final(const float* __restrict__ psum_rep, const int* __restrict__ batch,
                        const float* __restrict__ Wp, const float* __restrict__ bp,
                        float* __restrict__ out) {
    __shared__ float s_p[HID];
    int gi = blockIdx.x, e = threadIdx.x;   // 64 threads
    for (int f = e; f < HID; f += EMB) {
        float v = 0.f;
        #pragma unroll
        for (int r = 0; r < NREP; ++r)
            v += psum_rep[(size_t)r * N_GRAPHS * HID + gi * HID + f];
        s_p[f] = v;
    }
    int lane = e & 63;
    int r = 0;
    if (lane < 2) r = lower_bound_batch(batch, gi + lane);
    int c0 = __shfl(r, 0), c1 = __shfl(r, 1);
    float inv = 1.0f / fmaxf((float)(c1 - c0), 1.0f);
    __syncthreads();
    float acc = bp[e];
    #pragma unroll 8
    for (int f = 0; f < HID; ++f)
        acc = fmaf(s_p[f] * inv, Wp[f * EMB + e], acc);
    out[gi * EMB + e] = acc;
}

// ---------- launcher ----------

extern "C" void kernel_launch(void* const* d_in, const int* in_sizes, int n_in,
                              void* d_out, int out_size, void* d_ws, size_t ws_size,
                              hipStream_t stream) {
    const float* x   = (const float*)d_in[0];
    const int*   src = (const int*)d_in[1];
    const int*   dst = (const int*)d_in[2];
    const int* batch = (const int*)d_in[3];
    const float* W1 = (const float*)d_in[4];
    const float* b1 = (const float*)d_in[5];
    const float* W2 = (const float*)d_in[6];
    const float* b2 = (const float*)d_in[7];
    const float* W3 = (const float*)d_in[8];
    const float* b3 = (const float*)d_in[9];
    const float* g1 = (const float*)d_in[10];
    const float* be1 = (const float*)d_in[11];
    const float* g2 = (const float*)d_in[12];
    const float* be2 = (const float*)d_in[13];
    const float* g3 = (const float*)d_in[14];
    const float* be3 = (const float*)d_in[15];
    const float* Wp = (const float*)d_in[16];
    const float* bp = (const float*)d_in[17];
    float* out = (float*)d_out;

    char* ws = (char*)d_ws;
    size_t o = 0;
    auto alloc = [&](size_t bytes) {
        void* pp = ws + o;
        o += bytes;
        o = (o + 255) & ~255ull;
        return pp;
    };
    int*      cnt       = (int*)alloc(N_NODES * 4);
    int*      row_start = (int*)alloc((N_NODES + 1) * 4);
    int*      csum      = (int*)alloc(NCHUNK * 4);
    float*    dinv      = (float*)alloc(N_NODES * 4);
    int2*     e_pack    = (int2*)alloc((size_t)(N_EDGES + 8) * 8);
    _Float16* Wt2       = (_Float16*)alloc(HID * HID * 2);
    _Float16* Wt3       = (_Float16*)alloc(HID * HID * 2);
    float*    xp        = (float*)alloc((size_t)N_NODES * 8 * 4);
    unsigned int* H8a   = (unsigned int*)alloc((size_t)N_NODES * HID);  // fp8 rows
    unsigned int* H8b   = (unsigned int*)alloc((size_t)N_NODES * HID);
    float*    psum_rep  = (float*)alloc((size_t)NREP * N_GRAPHS * HID * 4);

    k_init<<<512, 256, 0, stream>>>(cnt, psum_rep, W2, W3, Wt2, Wt3, e_pack, x, xp);
    k_count<<<(N_EDGES + 255) / 256, 256, 0, stream>>>(dst, cnt);
    k_chunksum<<<NCHUNK, 256, 0, stream>>>(cnt, csum, dinv);
    k_scan<<<NCHUNK, 256, 0, stream>>>(cnt, csum, row_start);
    k_scatter<<<(N_EDGES + 255) / 256, 256, 0, stream>>>(src, dst, dinv, row_start,
                                                         cnt, e_pack);
    k_agg1<<<N_NODES / TB, 256, 0, stream>>>(xp, dinv, row_start, e_pack,
                                             W1, b1, g1, be1, (unsigned short*)H8a);
    k_fuse2<<<N_NODES / TB, 256, 0, stream>>>(H8a, dinv, row_start, e_pack, Wt2,
                                              b2, g2, be2, (unsigned char*)H8b);
    k_fuse3<<<N_NODES / TB, 256, 0, stream>>>(H8b, dinv, row_start, e_pack, Wt3,
                                              b3, g3, be3, batch, psum_rep);
    k_final<<<N_GRAPHS, EMB, 0, stream>>>(psum_rep, batch, Wp, bp, out);
}